// Round 2
// baseline (2255.308 us; speedup 1.0000x reference)
//
#include <hip/hip_runtime.h>

#define V 80000
#define E 640000
#define D 128
#define NREL 500
#define HALF (E/2)
#define NB_NODES 512
#define NGROUP 1000
#define EP (E + NGROUP * 32)   // padded edge capacity

typedef __attribute__((ext_vector_type(8))) short s8v;
typedef __attribute__((ext_vector_type(4))) float f4v;
typedef __attribute__((ext_vector_type(4))) int i4v;

__device__ __forceinline__ unsigned ord_enc(float f) {
  unsigned u = __float_as_uint(f);
  return (u & 0x80000000u) ? ~u : (u | 0x80000000u);
}
__device__ __forceinline__ float ord_dec(unsigned m) {
  return (m & 0x80000000u) ? __uint_as_float(m ^ 0x80000000u) : __uint_as_float(~m);
}
__device__ __forceinline__ unsigned short f2bf(float f) {
  unsigned u = __float_as_uint(f);
  return (unsigned short)((u + 0x7fffu + ((u >> 16) & 1u)) >> 16);
}

// zero/init everything: emax, esum, bn sums, hist, cnt2, padded sort arrays
__global__ void k_init(unsigned* emaxu, float* esum, float* colsum, float* colsumsq,
                       int* cnt, int* cnt2, float* coef, int* gsrc, int* gdst) {
  int i = blockIdx.x * 256 + threadIdx.x;
  if (i < V) { emaxu[i] = 0x007FFFFFu; esum[i] = 0.f; }
  if (i < D) { colsum[i] = 0.f; colsumsq[i] = 0.f; }
  if (i < 1024) { cnt[i] = 0; cnt2[i] = 0; }
  if (i < EP) { coef[i] = 0.f; gsrc[i] = 0; gdst[i] = 0; }
}

// out1 = rel @ w_rel ; rw[r] = rel[r] . attn_w[128:256]
__global__ void k_rel(const float* __restrict__ rel, const float* __restrict__ w_rel,
                      const float* __restrict__ attn_w, float* __restrict__ out1,
                      float* __restrict__ rw) {
  __shared__ float rs[D];
  __shared__ float red[D];
  int r = blockIdx.x, n = threadIdx.x;
  rs[n] = rel[r * D + n];
  __syncthreads();
  float acc = 0.f;
  #pragma unroll 8
  for (int j = 0; j < D; ++j) acc += rs[j] * w_rel[j * D + n];
  out1[r * D + n] = acc;
  red[n] = rs[n] * attn_w[D + n];
  __syncthreads();
  if (n == 0) {
    float s = 0.f;
    for (int j = 0; j < D; ++j) s += red[j];
    rw[r] = s;
  }
}

// Mloop[j,n] = sum_k loop_rel[(j+k)%128] * loop_w[k,n]
__global__ void k_mloop(const float* __restrict__ loop_rel, const float* __restrict__ loop_w,
                        float* __restrict__ mloop) {
  __shared__ float ls[D];
  int j = blockIdx.x, n = threadIdx.x;
  ls[n] = loop_rel[n];
  __syncthreads();
  float acc = 0.f;
  #pragma unroll 8
  for (int k = 0; k < D; ++k) acc += ls[(j + k) & 127] * loop_w[k * D + n];
  mloop[j * D + n] = acc;
}

// x -> bf16 copy
__global__ void k_xb(const float* __restrict__ x, unsigned short* __restrict__ xb) {
  int i = blockIdx.x * 256 + threadIdx.x;
  if (i * 4 >= V * D) return;
  f4v v = *(const f4v*)&x[i * 4];
  unsigned short o[4];
  o[0] = f2bf(v[0]); o[1] = f2bf(v[1]); o[2] = f2bf(v[2]); o[3] = f2bf(v[3]);
  *(unsigned long long*)&xb[i * 4] = *(unsigned long long*)o;
}

// MbT[g][n][j] = sum_k rel_t[(j+k)%128] * W_h[k][n], g = h*500+t, bf16
__global__ __launch_bounds__(256) void k_mbt(const float* __restrict__ rel,
    const float* __restrict__ in_w, const float* __restrict__ out_w,
    unsigned short* __restrict__ mbt) {
  __shared__ float Wsh[D * D];
  __shared__ float relp[2 * D];
  int g = blockIdx.x, tid = threadIdx.x;
  int t = (g >= NREL) ? g - NREL : g;
  const float* W = (g >= NREL) ? out_w : in_w;
  for (int idx = tid; idx < D * D; idx += 256) Wsh[idx] = W[idx];
  relp[tid] = rel[t * D + (tid & 127)];
  __syncthreads();
  int j = tid & 127, nh = tid >> 7;
  for (int n = nh * 64; n < nh * 64 + 64; ++n) {
    float acc = 0.f;
    #pragma unroll 8
    for (int k = 0; k < D; ++k) acc += relp[j + k] * Wsh[k * D + n];
    mbt[((size_t)g * D + n) * D + j] = f2bf(acc);
  }
}

// per node: sxw, dxw projections; out0 init = (x @ Mloop)/3 + bias
__global__ __launch_bounds__(256) void k_nodes(const float* __restrict__ x,
    const float* __restrict__ mloop, const float* __restrict__ attn_w,
    const float* __restrict__ bias, float* __restrict__ out0,
    float* __restrict__ sxw, float* __restrict__ dxw) {
  __shared__ float sW[D * D];
  __shared__ float xrow[4][D];
  int tid = threadIdx.x;
  for (int idx = tid; idx < D * D; idx += 256) sW[idx] = mloop[idx];
  __syncthreads();
  int wid = tid >> 6, lane = tid & 63;
  float ws0 = attn_w[lane], ws1 = attn_w[64 + lane];
  float wd0 = attn_w[256 + lane], wd1 = attn_w[320 + lane];
  float b0 = bias[2 * lane], b1 = bias[2 * lane + 1];
  float* xr = xrow[wid];
  for (int v = blockIdx.x * 4 + wid; v < V; v += NB_NODES * 4) {
    float x0 = x[v * D + lane], x1 = x[v * D + 64 + lane];
    float ps = x0 * ws0 + x1 * ws1;
    float pd = x0 * wd0 + x1 * wd1;
    #pragma unroll
    for (int off = 32; off; off >>= 1) { ps += __shfl_xor(ps, off); pd += __shfl_xor(pd, off); }
    if (lane == 0) { sxw[v] = ps; dxw[v] = pd; }
    xr[lane] = x0; xr[64 + lane] = x1;
    asm volatile("s_waitcnt lgkmcnt(0)" ::: "memory");
    float a0 = 0.f, a1 = 0.f;
    for (int j4 = 0; j4 < 32; ++j4) {
      float4 xv = *(const float4*)&xr[j4 * 4];
      #pragma unroll
      for (int jj = 0; jj < 4; ++jj) {
        int j = j4 * 4 + jj;
        float xs = (jj == 0) ? xv.x : (jj == 1) ? xv.y : (jj == 2) ? xv.z : xv.w;
        float2 wv = *(const float2*)&sW[j * D + 2 * lane];
        a0 += xs * wv.x; a1 += xs * wv.y;
      }
    }
    out0[v * D + 2 * lane]     = a0 * (1.f / 3.f) + b0;
    out0[v * D + 2 * lane + 1] = a1 * (1.f / 3.f) + b1;
    asm volatile("s_waitcnt lgkmcnt(0)" ::: "memory");
  }
}

// attention logits + segment max
__global__ void k_edge_e(const int* __restrict__ src, const int* __restrict__ dst,
                         const int* __restrict__ et, const float* __restrict__ sxw,
                         const float* __restrict__ dxw, const float* __restrict__ rw,
                         float* __restrict__ evals, unsigned* __restrict__ emaxu) {
  int i = blockIdx.x * 256 + threadIdx.x;
  if (i >= E) return;
  float ev = sxw[src[i]] + rw[et[i]] + dxw[dst[i]];
  ev = ev >= 0.f ? ev : 0.01f * ev;
  evals[i] = ev;
  atomicMax(&emaxu[dst[i]], ord_enc(ev));
}

// ee = exp(e - emax[dst]); esum += ee   (evals overwritten in place with ee)
__global__ void k_edge_ee(const int* __restrict__ dst, float* __restrict__ evals,
                          const unsigned* __restrict__ emaxu, float* __restrict__ esum) {
  int i = blockIdx.x * 256 + threadIdx.x;
  if (i >= E) return;
  int d = dst[i];
  float m = ord_dec(emaxu[d]);
  float xv = __expf(evals[i] - m);
  evals[i] = xv;
  atomicAdd(&esum[d], xv);
}

// histogram of group key
__global__ void k_hist(const int* __restrict__ et, int* __restrict__ cnt) {
  int i = blockIdx.x * 256 + threadIdx.x;
  if (i >= E) return;
  int g = et[i] + ((i >= HALF) ? NREL : 0);
  atomicAdd(&cnt[g], 1);
}

// exclusive scan of padded counts (single block, 1024 threads)
__global__ void k_scan(const int* __restrict__ cnt, int* __restrict__ poffs) {
  __shared__ int tmp[1024];
  int t = threadIdx.x;
  int c = (t < NGROUP) ? cnt[t] : 0;
  int pc = (c + 31) & ~31;
  tmp[t] = pc;
  __syncthreads();
  #pragma unroll
  for (int off = 1; off < 1024; off <<= 1) {
    int v = (t >= off) ? tmp[t - off] : 0;
    __syncthreads();
    tmp[t] += v;
    __syncthreads();
  }
  poffs[t] = tmp[t] - pc;
}

// scatter edges into sorted order + per-edge coefficient
__global__ void k_scatter(const int* __restrict__ src, const int* __restrict__ dst,
                          const int* __restrict__ et, const float* __restrict__ ee,
                          const float* __restrict__ esum, const float* __restrict__ enorm,
                          const int* __restrict__ poffs, int* __restrict__ cnt2,
                          int* __restrict__ gsrc, int* __restrict__ gdst,
                          float* __restrict__ coef) {
  int i = blockIdx.x * 256 + threadIdx.x;
  if (i >= E) return;
  int g = et[i] + ((i >= HALF) ? NREL : 0);
  int r = atomicAdd(&cnt2[g], 1);
  int pos = poffs[g] + r;
  int d = dst[i];
  gsrc[pos] = src[i];
  gdst[pos] = d;
  coef[pos] = ee[i] / esum[d] * enorm[i] * (1.f / 3.f);
}

// grouped gather-GEMM (MFMA) + row softmax + scaled atomic scatter
__global__ __launch_bounds__(256) void k_msg2(const unsigned short* __restrict__ xb,
    const unsigned short* __restrict__ mbt, const int* __restrict__ cnt,
    const int* __restrict__ poffs, const int* __restrict__ gsrc,
    const int* __restrict__ gdst, const float* __restrict__ coef,
    float* __restrict__ out0) {
  __shared__ uint4 Blds4[(D * 272) / 16];
  unsigned char* Bldsb = (unsigned char*)Blds4;
  int g = blockIdx.x;
  int c = cnt[g];
  if (c == 0) return;
  int tid = threadIdx.x;
  // stage MbT[g] (128 rows x 256B, pitch 272B)
  const uint4* Mg = (const uint4*)(mbt + (size_t)g * (D * D));
  #pragma unroll
  for (int i = 0; i < 8; ++i) {
    int idx = tid + i * 256;
    int row = idx >> 4, col = (idx & 15) * 16;
    Blds4[(row * 272 + col) >> 4] = Mg[idx];
  }
  __syncthreads();
  int wid = tid >> 6, ln = tid & 15, hi = (tid & 63) >> 4;
  int base0 = poffs[g];
  int nchunk = (c + 31) >> 5;
  for (int ch = wid; ch < nchunk; ch += 4) {
    int base = base0 + ch * 32;
    int sr0 = gsrc[base + ln];
    int sr1 = gsrc[base + 16 + ln];
    f4v cf0 = *(const f4v*)&coef[base + hi * 4];
    f4v cf1 = *(const f4v*)&coef[base + 16 + hi * 4];
    i4v dv0 = *(const i4v*)&gdst[base + hi * 4];
    i4v dv1 = *(const i4v*)&gdst[base + 16 + hi * 4];
    const unsigned short* xr0 = xb + (size_t)sr0 * D + hi * 8;
    const unsigned short* xr1 = xb + (size_t)sr1 * D + hi * 8;
    s8v af[2][4];
    #pragma unroll
    for (int kk = 0; kk < 4; ++kk) {
      af[0][kk] = *(const s8v*)(xr0 + kk * 32);
      af[1][kk] = *(const s8v*)(xr1 + kk * 32);
    }
    f4v acc[2][8];
    #pragma unroll
    for (int m = 0; m < 2; ++m)
      #pragma unroll
      for (int n = 0; n < 8; ++n) acc[m][n] = (f4v){0.f, 0.f, 0.f, 0.f};
    #pragma unroll
    for (int kk = 0; kk < 4; ++kk) {
      s8v bf[8];
      #pragma unroll
      for (int n = 0; n < 8; ++n) {
        int row = n * 16 + ln;
        bf[n] = *(const s8v*)(Bldsb + row * 272 + kk * 64 + hi * 16);
      }
      #pragma unroll
      for (int m = 0; m < 2; ++m)
        #pragma unroll
        for (int n = 0; n < 8; ++n)
          acc[m][n] = __builtin_amdgcn_mfma_f32_16x16x32_bf16(af[m][kk], bf[n], acc[m][n], 0, 0, 0);
    }
    // per-row softmax (rows spread over ln-lanes; hi*4+reg selects row) + scatter
    #pragma unroll
    for (int m = 0; m < 2; ++m) {
      f4v cf = m ? cf1 : cf0;
      i4v dv = m ? dv1 : dv0;
      f4v mx = acc[m][0];
      #pragma unroll
      for (int n = 1; n < 8; ++n)
        #pragma unroll
        for (int j = 0; j < 4; ++j) mx[j] = fmaxf(mx[j], acc[m][n][j]);
      #pragma unroll
      for (int off = 1; off < 16; off <<= 1)
        #pragma unroll
        for (int j = 0; j < 4; ++j) mx[j] = fmaxf(mx[j], __shfl_xor(mx[j], off));
      f4v sum = (f4v){0.f, 0.f, 0.f, 0.f};
      #pragma unroll
      for (int n = 0; n < 8; ++n)
        #pragma unroll
        for (int j = 0; j < 4; ++j) {
          float e = __expf(acc[m][n][j] - mx[j]);
          acc[m][n][j] = e;
          sum[j] += e;
        }
      #pragma unroll
      for (int off = 1; off < 16; off <<= 1)
        #pragma unroll
        for (int j = 0; j < 4; ++j) sum[j] += __shfl_xor(sum[j], off);
      f4v sc;
      #pragma unroll
      for (int j = 0; j < 4; ++j) sc[j] = cf[j] / sum[j];
      #pragma unroll
      for (int n = 0; n < 8; ++n)
        #pragma unroll
        for (int j = 0; j < 4; ++j)
          atomicAdd(&out0[(size_t)dv[j] * D + n * 16 + ln], acc[m][n][j] * sc[j]);
    }
  }
}

__global__ void k_bn_stats(const float* __restrict__ out0, float* __restrict__ colsum,
                           float* __restrict__ colsumsq) {
  int tid = threadIdx.x;
  int col = tid & 127;
  int v0 = blockIdx.x * 2 + (tid >> 7);
  float s = 0.f, s2 = 0.f;
  for (int v = v0; v < V; v += 1024) {
    float val = out0[v * D + col];
    s += val; s2 += val * val;
  }
  atomicAdd(&colsum[col], s);
  atomicAdd(&colsumsq[col], s2);
}

__global__ void k_bn_norm(float* __restrict__ out0, const float* __restrict__ colsum,
                          const float* __restrict__ colsumsq) {
  int i = blockIdx.x * 256 + threadIdx.x;
  if (i >= V * D) return;
  int c = i & 127;
  float mean = colsum[c] * (1.f / V);
  float var = colsumsq[c] * (1.f / V) - mean * mean;
  out0[i] = (out0[i] - mean) * rsqrtf(var + 1e-5f);
}

extern "C" void kernel_launch(void* const* d_in, const int* in_sizes, int n_in,
                              void* d_out, int out_size, void* d_ws, size_t ws_size,
                              hipStream_t stream) {
  const float* x        = (const float*)d_in[0];
  const float* rel      = (const float*)d_in[4];
  const float* enorm    = (const float*)d_in[5];
  const float* in_w     = (const float*)d_in[6];
  const float* out_w    = (const float*)d_in[7];
  const float* loop_w   = (const float*)d_in[8];
  const float* w_rel    = (const float*)d_in[9];
  const float* loop_rel = (const float*)d_in[10];
  const float* attn_w   = (const float*)d_in[11];
  const float* bias     = (const float*)d_in[12];
  const int* src = (const int*)d_in[13];
  const int* dst = (const int*)d_in[14];
  const int* et  = (const int*)d_in[15];

  float* out0 = (float*)d_out;           // [V,128]
  float* out1 = out0 + (size_t)V * D;    // [500,128]

  float* base = (float*)d_ws;
  size_t off = 0;
  float* sxw = base + off;      off += V;
  float* dxw = base + off;      off += V;
  float* esum = base + off;     off += V;
  unsigned* emaxu = (unsigned*)(base + off); off += V;
  float* evals = base + off;    off += E;      // later holds ee
  float* rw = base + off;       off += 512;
  float* mloop = base + off;    off += D * D;
  float* colsum = base + off;   off += 128;
  float* colsumsq = base + off; off += 128;
  int* cnt = (int*)(base + off);   off += 1024;
  int* cnt2 = (int*)(base + off);  off += 1024;
  int* poffs = (int*)(base + off); off += 1024;
  float* coef = base + off;     off += EP;
  int* gsrc = (int*)(base + off);  off += EP;
  int* gdst = (int*)(base + off);  off += EP;
  unsigned short* xb = (unsigned short*)(base + off);  off += (size_t)V * D / 2;
  unsigned short* mbt = (unsigned short*)(base + off); off += (size_t)NGROUP * D * D / 2;

  k_init<<<(EP + 255) / 256, 256, 0, stream>>>(emaxu, esum, colsum, colsumsq,
                                               cnt, cnt2, coef, gsrc, gdst);
  k_rel<<<NREL, D, 0, stream>>>(rel, w_rel, attn_w, out1, rw);
  k_mloop<<<D, D, 0, stream>>>(loop_rel, loop_w, mloop);
  k_xb<<<(V * D / 4 + 255) / 256, 256, 0, stream>>>(x, xb);
  k_mbt<<<NGROUP, 256, 0, stream>>>(rel, in_w, out_w, mbt);
  k_nodes<<<NB_NODES, 256, 0, stream>>>(x, mloop, attn_w, bias, out0, sxw, dxw);
  k_edge_e<<<(E + 255) / 256, 256, 0, stream>>>(src, dst, et, sxw, dxw, rw, evals, emaxu);
  k_edge_ee<<<(E + 255) / 256, 256, 0, stream>>>(dst, evals, emaxu, esum);
  k_hist<<<(E + 255) / 256, 256, 0, stream>>>(et, cnt);
  k_scan<<<1, 1024, 0, stream>>>(cnt, poffs);
  k_scatter<<<(E + 255) / 256, 256, 0, stream>>>(src, dst, et, evals, esum, enorm,
                                                 poffs, cnt2, gsrc, gdst, coef);
  k_msg2<<<NGROUP, 256, 0, stream>>>(xb, mbt, cnt, poffs, gsrc, gdst, coef, out0);
  k_bn_stats<<<512, 256, 0, stream>>>(out0, colsum, colsumsq);
  k_bn_norm<<<(V * D + 255) / 256, 256, 0, stream>>>(out0, colsum, colsumsq);
}

// Round 4
// 789.506 us; speedup vs baseline: 2.8566x; 2.8566x over previous
//
#include <hip/hip_runtime.h>

#define V 80000
#define E 640000
#define D 128
#define NREL 500
#define HALF (E/2)
#define NGROUP 1000
#define EP (E + NGROUP * 32)
#define NBLK_D ((V + 1023) / 1024)

typedef __attribute__((ext_vector_type(8))) short s8v;
typedef __attribute__((ext_vector_type(4))) float f4v;
typedef __attribute__((ext_vector_type(4))) int i4v;

__device__ __forceinline__ unsigned ord_enc(float f) {
  unsigned u = __float_as_uint(f);
  return (u & 0x80000000u) ? ~u : (u | 0x80000000u);
}
__device__ __forceinline__ float ord_dec(unsigned m) {
  return (m & 0x80000000u) ? __uint_as_float(m ^ 0x80000000u) : __uint_as_float(~m);
}
__device__ __forceinline__ unsigned short f2bf(float f) {
  unsigned u = __float_as_uint(f);
  return (unsigned short)((u + 0x7fffu + ((u >> 16) & 1u)) >> 16);
}

__global__ void k_init(unsigned* emaxu, float* esum, float* colsum, float* colsumsq,
                       int* cnt, int* cnt2, int* dcnt, int* dcnt2,
                       float* coef, int* gsrc, int* dposA) {
  int i = blockIdx.x * 256 + threadIdx.x;
  if (i < V) { emaxu[i] = 0x007FFFFFu; esum[i] = 0.f; dcnt[i] = 0; dcnt2[i] = 0; }
  if (i < D) { colsum[i] = 0.f; colsumsq[i] = 0.f; }
  if (i < 1024) { cnt[i] = 0; cnt2[i] = 0; }
  if (i < EP) { coef[i] = 0.f; gsrc[i] = 0; dposA[i] = -1; }
}

// out1 = rel @ w_rel ; rw[r] = rel[r] . attn_w[128:256]
__global__ void k_rel(const float* __restrict__ rel, const float* __restrict__ w_rel,
                      const float* __restrict__ attn_w, float* __restrict__ out1,
                      float* __restrict__ rw) {
  __shared__ float rs[D];
  __shared__ float red[D];
  int r = blockIdx.x, n = threadIdx.x;
  rs[n] = rel[r * D + n];
  __syncthreads();
  float acc = 0.f;
  #pragma unroll 8
  for (int j = 0; j < D; ++j) acc += rs[j] * w_rel[j * D + n];
  out1[r * D + n] = acc;
  red[n] = rs[n] * attn_w[D + n];
  __syncthreads();
  if (n == 0) {
    float s = 0.f;
    for (int j = 0; j < D; ++j) s += red[j];
    rw[r] = s;
  }
}

// mltb[n][j] = bf16( sum_k loop_rel[(j+k)%128] * loop_w[k][n] )   (transposed Mloop)
__global__ void k_mloop(const float* __restrict__ loop_rel, const float* __restrict__ loop_w,
                        unsigned short* __restrict__ mltb) {
  __shared__ float ls[2 * D];
  int j = blockIdx.x, n = threadIdx.x;
  ls[n] = loop_rel[n]; ls[n + D] = loop_rel[n];
  __syncthreads();
  float acc = 0.f;
  #pragma unroll 8
  for (int k = 0; k < D; ++k) acc += ls[j + k] * loop_w[k * D + n];
  mltb[n * D + j] = f2bf(acc);
}

__global__ void k_xb(const float* __restrict__ x, unsigned short* __restrict__ xb) {
  int i = blockIdx.x * 256 + threadIdx.x;
  if (i * 4 >= V * D) return;
  f4v v = *(const f4v*)&x[i * 4];
  unsigned short o[4];
  o[0] = f2bf(v[0]); o[1] = f2bf(v[1]); o[2] = f2bf(v[2]); o[3] = f2bf(v[3]);
  *(unsigned long long*)&xb[i * 4] = *(unsigned long long*)o;
}

__global__ void k_relb(const float* __restrict__ rel, unsigned short* __restrict__ relb) {
  int i = blockIdx.x * 256 + threadIdx.x;
  if (i < NREL * D) relb[i] = f2bf(rel[i]);
}

// wtb[h][n][k] = bf16(W_h[k][n])  (transposed weights)
__global__ void k_wtb(const float* __restrict__ in_w, const float* __restrict__ out_w,
                      unsigned short* __restrict__ wtb) {
  int b = blockIdx.x;
  int h = b >> 7, n = b & 127;
  const float* W = h ? out_w : in_w;
  int k = threadIdx.x;
  wtb[h * 16384 + n * D + k] = f2bf(W[k * D + n]);
}

// MbT[g][n][j] = sum_k rel_t[(j+k)%128] * W_h[k][n]  via MFMA
__global__ __launch_bounds__(256) void k_mbt2(const unsigned short* __restrict__ relb,
    const unsigned short* __restrict__ wtb, unsigned short* __restrict__ mbt) {
  __shared__ unsigned short relp[256];
  __shared__ unsigned short Wl[D * D];
  int g = blockIdx.x, tid = threadIdx.x;
  int t = (g >= NREL) ? g - NREL : g;
  const unsigned short* wt = wtb + (g >= NREL ? 16384 : 0);
  relp[tid] = relb[t * D + (tid & 127)];
  #pragma unroll
  for (int i = 0; i < 8; ++i) {               // FIX: 8 iterations = 2048 uint4 = full 128 rows
    int idx = tid + i * 256;
    int n = idx >> 4, kc = idx & 15;
    *(uint4*)((char*)Wl + n * 256 + ((kc ^ (n & 7)) << 4)) = *(const uint4*)(wt + n * D + kc * 8);
  }
  __syncthreads();
  int wid = tid >> 6, ln = tid & 15, hi = (tid & 63) >> 4;
  s8v af[2][4];
  #pragma unroll
  for (int m = 0; m < 2; ++m) {
    int j = wid * 32 + m * 16 + ln;
    #pragma unroll
    for (int ks = 0; ks < 4; ++ks) {
      int o = j + ks * 32 + hi * 8;
      s8v a;
      #pragma unroll
      for (int i = 0; i < 8; ++i) a[i] = (short)relp[o + i];
      af[m][ks] = a;
    }
  }
  f4v acc[2][8];
  #pragma unroll
  for (int m = 0; m < 2; ++m)
    #pragma unroll
    for (int nn = 0; nn < 8; ++nn) acc[m][nn] = (f4v){0.f, 0.f, 0.f, 0.f};
  #pragma unroll
  for (int ks = 0; ks < 4; ++ks) {
    #pragma unroll
    for (int nn = 0; nn < 8; ++nn) {
      int n2 = nn * 16 + ln;
      int kc = (ks * 4 + hi) ^ (n2 & 7);
      s8v b = *(const s8v*)((const char*)Wl + n2 * 256 + (kc << 4));
      #pragma unroll
      for (int m = 0; m < 2; ++m)
        acc[m][nn] = __builtin_amdgcn_mfma_f32_16x16x32_bf16(af[m][ks], b, acc[m][nn], 0, 0, 0);
    }
  }
  size_t gb = (size_t)g * (D * D);
  #pragma unroll
  for (int m = 0; m < 2; ++m)
    #pragma unroll
    for (int nn = 0; nn < 8; ++nn) {
      int jb = wid * 32 + m * 16 + hi * 4;
      unsigned long long pk = (unsigned long long)f2bf(acc[m][nn][0])
        | ((unsigned long long)f2bf(acc[m][nn][1]) << 16)
        | ((unsigned long long)f2bf(acc[m][nn][2]) << 32)
        | ((unsigned long long)f2bf(acc[m][nn][3]) << 48);
      *(unsigned long long*)&mbt[gb + (size_t)(nn * 16 + ln) * D + jb] = pk;
    }
}

// out0 init = (xb @ MloopT^T)/3 + bias  via MFMA
__global__ __launch_bounds__(256) void k_lgemm(const unsigned short* __restrict__ xb,
    const unsigned short* __restrict__ mltb, const float* __restrict__ bias,
    float* __restrict__ out0) {
  __shared__ unsigned short Wl[D * D];
  int tid = threadIdx.x;
  #pragma unroll
  for (int i = 0; i < 8; ++i) {               // FIX: 8 iterations = full 128 rows
    int idx = tid + i * 256;
    int n = idx >> 4, kc = idx & 15;
    *(uint4*)((char*)Wl + n * 256 + ((kc ^ (n & 7)) << 4)) = *(const uint4*)(mltb + n * D + kc * 8);
  }
  __syncthreads();
  int wid = tid >> 6, ln = tid & 15, hi = (tid & 63) >> 4;
  int rbase = blockIdx.x * 128 + wid * 32;
  s8v af[2][4];
  #pragma unroll
  for (int m = 0; m < 2; ++m)
    #pragma unroll
    for (int ks = 0; ks < 4; ++ks)
      af[m][ks] = *(const s8v*)(xb + (size_t)(rbase + m * 16 + ln) * D + ks * 32 + hi * 8);
  f4v acc[2][8];
  #pragma unroll
  for (int m = 0; m < 2; ++m)
    #pragma unroll
    for (int nn = 0; nn < 8; ++nn) acc[m][nn] = (f4v){0.f, 0.f, 0.f, 0.f};
  #pragma unroll
  for (int ks = 0; ks < 4; ++ks) {
    #pragma unroll
    for (int nn = 0; nn < 8; ++nn) {
      int n2 = nn * 16 + ln;
      int kc = (ks * 4 + hi) ^ (n2 & 7);
      s8v b = *(const s8v*)((const char*)Wl + n2 * 256 + (kc << 4));
      #pragma unroll
      for (int m = 0; m < 2; ++m)
        acc[m][nn] = __builtin_amdgcn_mfma_f32_16x16x32_bf16(af[m][ks], b, acc[m][nn], 0, 0, 0);
    }
  }
  float bcol[8];
  #pragma unroll
  for (int nn = 0; nn < 8; ++nn) bcol[nn] = bias[nn * 16 + ln];
  #pragma unroll
  for (int m = 0; m < 2; ++m)
    #pragma unroll
    for (int nn = 0; nn < 8; ++nn)
      #pragma unroll
      for (int r = 0; r < 4; ++r)
        out0[(size_t)(rbase + m * 16 + hi * 4 + r) * D + nn * 16 + ln] =
            acc[m][nn][r] * (1.f / 3.f) + bcol[nn];
}

// per-node attention projections
__global__ void k_proj(const float* __restrict__ x, const float* __restrict__ attn_w,
                       float* __restrict__ sxw, float* __restrict__ dxw) {
  int tid = threadIdx.x;
  int wid = tid >> 6, lane = tid & 63;
  float ws0 = attn_w[lane], ws1 = attn_w[64 + lane];
  float wd0 = attn_w[256 + lane], wd1 = attn_w[320 + lane];
  for (int v = blockIdx.x * 4 + wid; v < V; v += 640 * 4) {
    float x0 = x[(size_t)v * D + lane], x1 = x[(size_t)v * D + 64 + lane];
    float ps = x0 * ws0 + x1 * ws1;
    float pd = x0 * wd0 + x1 * wd1;
    #pragma unroll
    for (int off = 32; off; off >>= 1) { ps += __shfl_xor(ps, off); pd += __shfl_xor(pd, off); }
    if (lane == 0) { sxw[v] = ps; dxw[v] = pd; }
  }
}

// attention logits + segment max + both histograms
__global__ void k_edge_e(const int* __restrict__ src, const int* __restrict__ dst,
                         const int* __restrict__ et, const float* __restrict__ sxw,
                         const float* __restrict__ dxw, const float* __restrict__ rw,
                         float* __restrict__ evals, unsigned* __restrict__ emaxu,
                         int* __restrict__ cnt, int* __restrict__ dcnt) {
  int i = blockIdx.x * 256 + threadIdx.x;
  if (i >= E) return;
  int d = dst[i];
  float ev = sxw[src[i]] + rw[et[i]] + dxw[d];
  ev = ev >= 0.f ? ev : 0.01f * ev;
  evals[i] = ev;
  atomicMax(&emaxu[d], ord_enc(ev));
  atomicAdd(&cnt[et[i] + ((i >= HALF) ? NREL : 0)], 1);
  atomicAdd(&dcnt[d], 1);
}

__global__ void k_edge_ee(const int* __restrict__ dst, float* __restrict__ evals,
                          const unsigned* __restrict__ emaxu, float* __restrict__ esum) {
  int i = blockIdx.x * 256 + threadIdx.x;
  if (i >= E) return;
  int d = dst[i];
  float m = ord_dec(emaxu[d]);
  float xv = __expf(evals[i] - m);
  evals[i] = xv;
  atomicAdd(&esum[d], xv);
}

// group scan (padded to 32)
__global__ void k_scan(const int* __restrict__ cnt, int* __restrict__ poffs) {
  __shared__ int tmp[1024];
  int t = threadIdx.x;
  int c = (t < NGROUP) ? cnt[t] : 0;
  int pc = (c + 31) & ~31;
  tmp[t] = pc;
  __syncthreads();
  #pragma unroll
  for (int off = 1; off < 1024; off <<= 1) {
    int v = (t >= off) ? tmp[t - off] : 0;
    __syncthreads();
    tmp[t] += v;
    __syncthreads();
  }
  poffs[t] = tmp[t] - pc;
}

__global__ void k_dscan1(const int* __restrict__ dcnt, int* __restrict__ dloc,
                         int* __restrict__ dtot) {
  __shared__ int tmp[1024];
  int t = threadIdx.x, i = blockIdx.x * 1024 + t;
  int v = (i < V) ? dcnt[i] : 0;
  tmp[t] = v;
  __syncthreads();
  #pragma unroll
  for (int off = 1; off < 1024; off <<= 1) {
    int u = (t >= off) ? tmp[t - off] : 0;
    __syncthreads();
    tmp[t] += u;
    __syncthreads();
  }
  if (i < V) dloc[i] = tmp[t] - v;
  if (t == 1023) dtot[blockIdx.x] = tmp[t];
}

__global__ void k_dscan2(const int* __restrict__ dtot, int* __restrict__ dboff) {
  __shared__ int tmp[128];
  int t = threadIdx.x;
  int v = (t < NBLK_D) ? dtot[t] : 0;
  tmp[t] = v;
  __syncthreads();
  #pragma unroll
  for (int off = 1; off < 128; off <<= 1) {
    int u = (t >= off) ? tmp[t - off] : 0;
    __syncthreads();
    tmp[t] += u;
    __syncthreads();
  }
  dboff[t] = tmp[t] - v;
}

__global__ void k_dscan3(const int* __restrict__ dloc, const int* __restrict__ dboff,
                         int* __restrict__ doffs) {
  int i = blockIdx.x * 1024 + threadIdx.x;
  if (i < V) doffs[i] = dloc[i] + dboff[i >> 10];
}

__global__ void k_scatter(const int* __restrict__ src, const int* __restrict__ dst,
                          const int* __restrict__ et, const float* __restrict__ ee,
                          const float* __restrict__ esum, const float* __restrict__ enorm,
                          const int* __restrict__ poffs, int* __restrict__ cnt2,
                          const int* __restrict__ doffs, int* __restrict__ dcnt2,
                          int* __restrict__ gsrc, int* __restrict__ dposA,
                          float* __restrict__ coef) {
  int i = blockIdx.x * 256 + threadIdx.x;
  if (i >= E) return;
  int g = et[i] + ((i >= HALF) ? NREL : 0);
  int pos = poffs[g] + atomicAdd(&cnt2[g], 1);
  int d = dst[i];
  gsrc[pos] = src[i];
  coef[pos] = ee[i] / esum[d] * enorm[i] * (1.f / 3.f);
  int dr = atomicAdd(&dcnt2[d], 1);
  dposA[pos] = doffs[d] + dr;
}

// grouped gather-GEMM + softmax + scaled write to dst-sorted msgb
__global__ __launch_bounds__(256) void k_msg3(const unsigned short* __restrict__ xb,
    const unsigned short* __restrict__ mbt, const int* __restrict__ cnt,
    const int* __restrict__ poffs, const int* __restrict__ gsrc,
    const int* __restrict__ dposA, const float* __restrict__ coef,
    const int* __restrict__ doffs, int loNode, int hiNode,
    unsigned short* __restrict__ msgb) {
  __shared__ uint4 Blds4[(D * 272) / 16];
  unsigned char* Bldsb = (unsigned char*)Blds4;
  int g = blockIdx.x;
  int c = cnt[g];
  if (c == 0) return;
  int tid = threadIdx.x;
  const uint4* Mg = (const uint4*)(mbt + (size_t)g * (D * D));
  #pragma unroll
  for (int i = 0; i < 8; ++i) {
    int idx = tid + i * 256;
    int row = idx >> 4, col = (idx & 15) * 16;
    Blds4[(row * 272 + col) >> 4] = Mg[idx];
  }
  __syncthreads();
  int b1 = doffs[loNode];
  int b2 = (hiNode >= V) ? E : doffs[hiNode];
  int wid = tid >> 6, ln = tid & 15, hi = (tid & 63) >> 4;
  int base0 = poffs[g];
  int nchunk = (c + 31) >> 5;
  for (int ch = wid; ch < nchunk; ch += 4) {
    int base = base0 + ch * 32;
    int sr0 = gsrc[base + ln];
    int sr1 = gsrc[base + 16 + ln];
    f4v cf0 = *(const f4v*)&coef[base + hi * 4];
    f4v cf1 = *(const f4v*)&coef[base + 16 + hi * 4];
    i4v dp0 = *(const i4v*)&dposA[base + hi * 4];
    i4v dp1 = *(const i4v*)&dposA[base + 16 + hi * 4];
    const unsigned short* xr0 = xb + (size_t)sr0 * D + hi * 8;
    const unsigned short* xr1 = xb + (size_t)sr1 * D + hi * 8;
    s8v af[2][4];
    #pragma unroll
    for (int kk = 0; kk < 4; ++kk) {
      af[0][kk] = *(const s8v*)(xr0 + kk * 32);
      af[1][kk] = *(const s8v*)(xr1 + kk * 32);
    }
    f4v acc[2][8];
    #pragma unroll
    for (int m = 0; m < 2; ++m)
      #pragma unroll
      for (int n = 0; n < 8; ++n) acc[m][n] = (f4v){0.f, 0.f, 0.f, 0.f};
    #pragma unroll
    for (int kk = 0; kk < 4; ++kk) {
      s8v bf[8];
      #pragma unroll
      for (int n = 0; n < 8; ++n) {
        int row = n * 16 + ln;
        bf[n] = *(const s8v*)(Bldsb + row * 272 + kk * 64 + hi * 16);
      }
      #pragma unroll
      for (int m = 0; m < 2; ++m)
        #pragma unroll
        for (int n = 0; n < 8; ++n)
          acc[m][n] = __builtin_amdgcn_mfma_f32_16x16x32_bf16(af[m][kk], bf[n], acc[m][n], 0, 0, 0);
    }
    #pragma unroll
    for (int m = 0; m < 2; ++m) {
      f4v cf = m ? cf1 : cf0;
      i4v dp = m ? dp1 : dp0;
      f4v mx = acc[m][0];
      #pragma unroll
      for (int n = 1; n < 8; ++n)
        #pragma unroll
        for (int j = 0; j < 4; ++j) mx[j] = fmaxf(mx[j], acc[m][n][j]);
      #pragma unroll
      for (int off = 1; off < 16; off <<= 1)
        #pragma unroll
        for (int j = 0; j < 4; ++j) mx[j] = fmaxf(mx[j], __shfl_xor(mx[j], off));
      f4v sum = (f4v){0.f, 0.f, 0.f, 0.f};
      #pragma unroll
      for (int n = 0; n < 8; ++n)
        #pragma unroll
        for (int j = 0; j < 4; ++j) {
          float e = __expf(acc[m][n][j] - mx[j]);
          acc[m][n][j] = e;
          sum[j] += e;
        }
      #pragma unroll
      for (int off = 1; off < 16; off <<= 1)
        #pragma unroll
        for (int j = 0; j < 4; ++j) sum[j] += __shfl_xor(sum[j], off);
      #pragma unroll
      for (int j = 0; j < 4; ++j) {
        int dpos = dp[j];
        if (dpos >= b1 && dpos < b2) {
          size_t rowb = (size_t)(dpos - b1) * D;
          float s = cf[j] / sum[j];
          #pragma unroll
          for (int n = 0; n < 8; ++n)
            msgb[rowb + n * 16 + ln] = f2bf(acc[m][n][j] * s);
        }
      }
    }
  }
}

// per-node segment sum of dst-sorted messages into out0
__global__ void k_sum(const unsigned short* __restrict__ msgb, const int* __restrict__ doffs,
                      const int* __restrict__ dcnt, float* __restrict__ out0,
                      int loNode, int hiNode) {
  int d = loNode + blockIdx.x * 4 + (threadIdx.x >> 6);
  if (d >= hiNode) return;
  int lane = threadIdx.x & 63;
  int b1 = doffs[loNode];
  int start = doffs[d] - b1, len = dcnt[d];
  float a0 = 0.f, a1 = 0.f;
  const unsigned short* mp = msgb + (size_t)start * D + lane * 2;
  for (int r = 0; r < len; ++r) {
    unsigned u = *(const unsigned*)(mp + (size_t)r * D);
    a0 += __uint_as_float(u << 16);
    a1 += __uint_as_float(u & 0xffff0000u);
  }
  float2* o = (float2*)&out0[(size_t)d * D + lane * 2];
  float2 v = *o;
  v.x += a0; v.y += a1;
  *o = v;
}

__global__ void k_bn_stats(const float* __restrict__ out0, float* __restrict__ colsum,
                           float* __restrict__ colsumsq) {
  int tid = threadIdx.x;
  int col = tid & 127;
  int v0 = blockIdx.x * 2 + (tid >> 7);
  float s = 0.f, s2 = 0.f;
  for (int v = v0; v < V; v += 1024) {
    float val = out0[(size_t)v * D + col];
    s += val; s2 += val * val;
  }
  atomicAdd(&colsum[col], s);
  atomicAdd(&colsumsq[col], s2);
}

__global__ void k_bn_norm(float* __restrict__ out0, const float* __restrict__ colsum,
                          const float* __restrict__ colsumsq) {
  int i = blockIdx.x * 256 + threadIdx.x;
  if (i >= V * D) return;
  int c = i & 127;
  float mean = colsum[c] * (1.f / V);
  float var = colsumsq[c] * (1.f / V) - mean * mean;
  out0[i] = (out0[i] - mean) * rsqrtf(var + 1e-5f);
}

extern "C" void kernel_launch(void* const* d_in, const int* in_sizes, int n_in,
                              void* d_out, int out_size, void* d_ws, size_t ws_size,
                              hipStream_t stream) {
  const float* x        = (const float*)d_in[0];
  const float* rel      = (const float*)d_in[4];
  const float* enorm    = (const float*)d_in[5];
  const float* in_w     = (const float*)d_in[6];
  const float* out_w    = (const float*)d_in[7];
  const float* loop_w   = (const float*)d_in[8];
  const float* w_rel    = (const float*)d_in[9];
  const float* loop_rel = (const float*)d_in[10];
  const float* attn_w   = (const float*)d_in[11];
  const float* bias     = (const float*)d_in[12];
  const int* src = (const int*)d_in[13];
  const int* dst = (const int*)d_in[14];
  const int* et  = (const int*)d_in[15];

  float* out0 = (float*)d_out;
  float* out1 = out0 + (size_t)V * D;

  float* base = (float*)d_ws;
  size_t off = 0;
  float* sxw = base + off;      off += V;
  float* dxw = base + off;      off += V;
  float* esum = base + off;     off += V;
  unsigned* emaxu = (unsigned*)(base + off); off += V;
  float* evals = base + off;    off += E;
  float* rw = base + off;       off += 512;
  float* colsum = base + off;   off += 128;
  float* colsumsq = base + off; off += 128;
  int* cnt = (int*)(base + off);   off += 1024;
  int* cnt2 = (int*)(base + off);  off += 1024;
  int* poffs = (int*)(base + off); off += 1024;
  int* dcnt = (int*)(base + off);  off += V;
  int* dcnt2 = (int*)(base + off); off += V;
  int* dloc = (int*)(base + off);  off += V;
  int* doffs = (int*)(base + off); off += V;
  int* dtot = (int*)(base + off);  off += 128;
  int* dboff = (int*)(base + off); off += 128;
  float* coef = base + off;        off += EP;
  int* gsrc = (int*)(base + off);  off += EP;
  int* dposA = (int*)(base + off); off += EP;
  unsigned short* mltb = (unsigned short*)(base + off); off += D * D / 2;
  unsigned short* relb = (unsigned short*)(base + off); off += NREL * D / 2;
  unsigned short* wtb  = (unsigned short*)(base + off); off += 2 * D * D / 2;
  unsigned short* xb   = (unsigned short*)(base + off); off += (size_t)V * D / 2;
  unsigned short* mbt  = (unsigned short*)(base + off); off += (size_t)NGROUP * D * D / 2;
  unsigned short* msgb = (unsigned short*)(base + off);

  // adaptive slab count for msgb (each edge row = 128 bf16 = 64 float-equivs)
  size_t availF = (ws_size / 4 > off) ? (ws_size / 4 - off) : 0;
  int ns = 1;
  if ((size_t)EP * (D / 2) > availF) {
    ns = 2;
    while (ns < 64 && (size_t)(E / ns + 16384) * (D / 2) > availF) ns *= 2;
  }

  k_init<<<(EP + 255) / 256, 256, 0, stream>>>(emaxu, esum, colsum, colsumsq,
                                               cnt, cnt2, dcnt, dcnt2, coef, gsrc, dposA);
  k_rel<<<NREL, D, 0, stream>>>(rel, w_rel, attn_w, out1, rw);
  k_mloop<<<D, D, 0, stream>>>(loop_rel, loop_w, mltb);
  k_xb<<<(V * D / 4 + 255) / 256, 256, 0, stream>>>(x, xb);
  k_relb<<<(NREL * D + 255) / 256, 256, 0, stream>>>(rel, relb);
  k_wtb<<<256, D, 0, stream>>>(in_w, out_w, wtb);
  k_mbt2<<<NGROUP, 256, 0, stream>>>(relb, wtb, mbt);
  k_proj<<<640, 256, 0, stream>>>(x, attn_w, sxw, dxw);
  k_lgemm<<<V / 128, 256, 0, stream>>>(xb, mltb, bias, out0);
  k_edge_e<<<(E + 255) / 256, 256, 0, stream>>>(src, dst, et, sxw, dxw, rw, evals, emaxu, cnt, dcnt);
  k_edge_ee<<<(E + 255) / 256, 256, 0, stream>>>(dst, evals, emaxu, esum);
  k_scan<<<1, 1024, 0, stream>>>(cnt, poffs);
  k_dscan1<<<NBLK_D, 1024, 0, stream>>>(dcnt, dloc, dtot);
  k_dscan2<<<1, 128, 0, stream>>>(dtot, dboff);
  k_dscan3<<<NBLK_D, 1024, 0, stream>>>(dloc, dboff, doffs);
  k_scatter<<<(E + 255) / 256, 256, 0, stream>>>(src, dst, et, evals, esum, enorm,
                                                 poffs, cnt2, doffs, dcnt2, gsrc, dposA, coef);
  int Vs = V / ns;
  for (int s = 0; s < ns; ++s) {
    int lo = s * Vs, hi = (s == ns - 1) ? V : (s + 1) * Vs;
    k_msg3<<<NGROUP, 256, 0, stream>>>(xb, mbt, cnt, poffs, gsrc, dposA, coef,
                                       doffs, lo, hi, msgb);
    k_sum<<<(Vs + 3) / 4, 256, 0, stream>>>(msgb, doffs, dcnt, out0, lo, hi);
  }
  k_bn_stats<<<512, 256, 0, stream>>>(out0, colsum, colsumsq);
  k_bn_norm<<<(V * D + 255) / 256, 256, 0, stream>>>(out0, colsum, colsumsq);
}

// Round 5
// 546.056 us; speedup vs baseline: 4.1302x; 1.4458x over previous
//
#include <hip/hip_runtime.h>

#define V 80000
#define E 640000
#define D 128
#define NREL 500
#define HALF (E/2)
#define NGROUP 1000
#define EP (E + NGROUP * 32)
#define NBLK_D ((V + 1023) / 1024)
#define NREP 160
#define SLAB 4000   // E / NREP

typedef __attribute__((ext_vector_type(8))) short s8v;
typedef __attribute__((ext_vector_type(4))) float f4v;
typedef __attribute__((ext_vector_type(4))) int i4v;

__device__ __forceinline__ unsigned short f2bf(float f) {
  unsigned u = __float_as_uint(f);
  return (unsigned short)((u + 0x7fffu + ((u >> 16) & 1u)) >> 16);
}

__global__ void k_init(float* esum, float* colsum, float* colsumsq,
                       int* dcnt, int* dcnt2, int* hist, int* cnt2rep,
                       float* coef, int* gsrc, int* dposA) {
  int i = blockIdx.x * 256 + threadIdx.x;
  if (i < V) { esum[i] = 0.f; dcnt[i] = 0; dcnt2[i] = 0; }
  if (i < D) { colsum[i] = 0.f; colsumsq[i] = 0.f; }
  if (i < NGROUP * NREP) { hist[i] = 0; cnt2rep[i] = 0; }
  if (i < EP) { coef[i] = 0.f; gsrc[i] = 0; dposA[i] = -1; }
}

// out1 = rel @ w_rel ; rw[r] = rel[r] . attn_w[128:256]
__global__ void k_rel(const float* __restrict__ rel, const float* __restrict__ w_rel,
                      const float* __restrict__ attn_w, float* __restrict__ out1,
                      float* __restrict__ rw) {
  __shared__ float rs[D];
  __shared__ float red[D];
  int r = blockIdx.x, n = threadIdx.x;
  rs[n] = rel[r * D + n];
  __syncthreads();
  float acc = 0.f;
  #pragma unroll 8
  for (int j = 0; j < D; ++j) acc += rs[j] * w_rel[j * D + n];
  out1[r * D + n] = acc;
  red[n] = rs[n] * attn_w[D + n];
  __syncthreads();
  if (n == 0) {
    float s = 0.f;
    for (int j = 0; j < D; ++j) s += red[j];
    rw[r] = s;
  }
}

// mltb[n][j] = bf16( sum_k loop_rel[(j+k)%128] * loop_w[k][n] )
__global__ void k_mloop(const float* __restrict__ loop_rel, const float* __restrict__ loop_w,
                        unsigned short* __restrict__ mltb) {
  __shared__ float ls[2 * D];
  int j = blockIdx.x, n = threadIdx.x;
  ls[n] = loop_rel[n]; ls[n + D] = loop_rel[n];
  __syncthreads();
  float acc = 0.f;
  #pragma unroll 8
  for (int k = 0; k < D; ++k) acc += ls[j + k] * loop_w[k * D + n];
  mltb[n * D + j] = f2bf(acc);
}

__global__ void k_xb(const float* __restrict__ x, unsigned short* __restrict__ xb) {
  int i = blockIdx.x * 256 + threadIdx.x;
  if (i * 4 >= V * D) return;
  f4v v = *(const f4v*)&x[i * 4];
  unsigned short o[4];
  o[0] = f2bf(v[0]); o[1] = f2bf(v[1]); o[2] = f2bf(v[2]); o[3] = f2bf(v[3]);
  *(unsigned long long*)&xb[i * 4] = *(unsigned long long*)o;
}

__global__ void k_relb(const float* __restrict__ rel, unsigned short* __restrict__ relb) {
  int i = blockIdx.x * 256 + threadIdx.x;
  if (i < NREL * D) relb[i] = f2bf(rel[i]);
}

// wtb[h][n][k] = bf16(W_h[k][n])
__global__ void k_wtb(const float* __restrict__ in_w, const float* __restrict__ out_w,
                      unsigned short* __restrict__ wtb) {
  int b = blockIdx.x;
  int h = b >> 7, n = b & 127;
  const float* W = h ? out_w : in_w;
  int k = threadIdx.x;
  wtb[h * 16384 + n * D + k] = f2bf(W[k * D + n]);
}

// MbT[g][n][j] = sum_k rel_t[(j+k)%128] * W_h[k][n]  via MFMA
__global__ __launch_bounds__(256) void k_mbt2(const unsigned short* __restrict__ relb,
    const unsigned short* __restrict__ wtb, unsigned short* __restrict__ mbt) {
  __shared__ unsigned short relp[256];
  __shared__ unsigned short Wl[D * D];
  int g = blockIdx.x, tid = threadIdx.x;
  int t = (g >= NREL) ? g - NREL : g;
  const unsigned short* wt = wtb + (g >= NREL ? 16384 : 0);
  relp[tid] = relb[t * D + (tid & 127)];
  #pragma unroll
  for (int i = 0; i < 8; ++i) {
    int idx = tid + i * 256;
    int n = idx >> 4, kc = idx & 15;
    *(uint4*)((char*)Wl + n * 256 + ((kc ^ (n & 7)) << 4)) = *(const uint4*)(wt + n * D + kc * 8);
  }
  __syncthreads();
  int wid = tid >> 6, ln = tid & 15, hi = (tid & 63) >> 4;
  s8v af[2][4];
  #pragma unroll
  for (int m = 0; m < 2; ++m) {
    int j = wid * 32 + m * 16 + ln;
    #pragma unroll
    for (int ks = 0; ks < 4; ++ks) {
      int o = j + ks * 32 + hi * 8;
      s8v a;
      #pragma unroll
      for (int i = 0; i < 8; ++i) a[i] = (short)relp[o + i];
      af[m][ks] = a;
    }
  }
  f4v acc[2][8];
  #pragma unroll
  for (int m = 0; m < 2; ++m)
    #pragma unroll
    for (int nn = 0; nn < 8; ++nn) acc[m][nn] = (f4v){0.f, 0.f, 0.f, 0.f};
  #pragma unroll
  for (int ks = 0; ks < 4; ++ks) {
    #pragma unroll
    for (int nn = 0; nn < 8; ++nn) {
      int n2 = nn * 16 + ln;
      int kc = (ks * 4 + hi) ^ (n2 & 7);
      s8v b = *(const s8v*)((const char*)Wl + n2 * 256 + (kc << 4));
      #pragma unroll
      for (int m = 0; m < 2; ++m)
        acc[m][nn] = __builtin_amdgcn_mfma_f32_16x16x32_bf16(af[m][ks], b, acc[m][nn], 0, 0, 0);
    }
  }
  size_t gb = (size_t)g * (D * D);
  #pragma unroll
  for (int m = 0; m < 2; ++m)
    #pragma unroll
    for (int nn = 0; nn < 8; ++nn) {
      int jb = wid * 32 + m * 16 + hi * 4;
      unsigned long long pk = (unsigned long long)f2bf(acc[m][nn][0])
        | ((unsigned long long)f2bf(acc[m][nn][1]) << 16)
        | ((unsigned long long)f2bf(acc[m][nn][2]) << 32)
        | ((unsigned long long)f2bf(acc[m][nn][3]) << 48);
      *(unsigned long long*)&mbt[gb + (size_t)(nn * 16 + ln) * D + jb] = pk;
    }
}

// out0 init = (xb @ MloopT^T)/3 + bias  via MFMA
__global__ __launch_bounds__(256) void k_lgemm(const unsigned short* __restrict__ xb,
    const unsigned short* __restrict__ mltb, const float* __restrict__ bias,
    float* __restrict__ out0) {
  __shared__ unsigned short Wl[D * D];
  int tid = threadIdx.x;
  #pragma unroll
  for (int i = 0; i < 8; ++i) {
    int idx = tid + i * 256;
    int n = idx >> 4, kc = idx & 15;
    *(uint4*)((char*)Wl + n * 256 + ((kc ^ (n & 7)) << 4)) = *(const uint4*)(mltb + n * D + kc * 8);
  }
  __syncthreads();
  int wid = tid >> 6, ln = tid & 15, hi = (tid & 63) >> 4;
  int rbase = blockIdx.x * 128 + wid * 32;
  s8v af[2][4];
  #pragma unroll
  for (int m = 0; m < 2; ++m)
    #pragma unroll
    for (int ks = 0; ks < 4; ++ks)
      af[m][ks] = *(const s8v*)(xb + (size_t)(rbase + m * 16 + ln) * D + ks * 32 + hi * 8);
  f4v acc[2][8];
  #pragma unroll
  for (int m = 0; m < 2; ++m)
    #pragma unroll
    for (int nn = 0; nn < 8; ++nn) acc[m][nn] = (f4v){0.f, 0.f, 0.f, 0.f};
  #pragma unroll
  for (int ks = 0; ks < 4; ++ks) {
    #pragma unroll
    for (int nn = 0; nn < 8; ++nn) {
      int n2 = nn * 16 + ln;
      int kc = (ks * 4 + hi) ^ (n2 & 7);
      s8v b = *(const s8v*)((const char*)Wl + n2 * 256 + (kc << 4));
      #pragma unroll
      for (int m = 0; m < 2; ++m)
        acc[m][nn] = __builtin_amdgcn_mfma_f32_16x16x32_bf16(af[m][ks], b, acc[m][nn], 0, 0, 0);
    }
  }
  float bcol[8];
  #pragma unroll
  for (int nn = 0; nn < 8; ++nn) bcol[nn] = bias[nn * 16 + ln];
  #pragma unroll
  for (int m = 0; m < 2; ++m)
    #pragma unroll
    for (int nn = 0; nn < 8; ++nn)
      #pragma unroll
      for (int r = 0; r < 4; ++r)
        out0[(size_t)(rbase + m * 16 + hi * 4 + r) * D + nn * 16 + ln] =
            acc[m][nn][r] * (1.f / 3.f) + bcol[nn];
}

// per-node attention projections
__global__ void k_proj(const float* __restrict__ x, const float* __restrict__ attn_w,
                       float* __restrict__ sxw, float* __restrict__ dxw) {
  int tid = threadIdx.x;
  int wid = tid >> 6, lane = tid & 63;
  float ws0 = attn_w[lane], ws1 = attn_w[64 + lane];
  float wd0 = attn_w[256 + lane], wd1 = attn_w[320 + lane];
  for (int v = blockIdx.x * 4 + wid; v < V; v += 640 * 4) {
    float x0 = x[(size_t)v * D + lane], x1 = x[(size_t)v * D + 64 + lane];
    float ps = x0 * ws0 + x1 * ws1;
    float pd = x0 * wd0 + x1 * wd1;
    #pragma unroll
    for (int off = 32; off; off >>= 1) { ps += __shfl_xor(ps, off); pd += __shfl_xor(pd, off); }
    if (lane == 0) { sxw[v] = ps; dxw[v] = pd; }
  }
}

// fused per-edge phase A: logits -> ee=exp (no max subtraction; |e| small),
// esum/dcnt atomics (80K bins, low contention), replica-sharded group hist
__global__ void k_edge(const int* __restrict__ src, const int* __restrict__ dst,
                       const int* __restrict__ et, const float* __restrict__ sxw,
                       const float* __restrict__ dxw, const float* __restrict__ rw,
                       float* __restrict__ evals, float* __restrict__ esum,
                       int* __restrict__ dcnt, int* __restrict__ hist) {
  int i = blockIdx.x * 256 + threadIdx.x;
  if (i >= E) return;
  int d = dst[i];
  float ev = sxw[src[i]] + rw[et[i]] + dxw[d];
  ev = ev >= 0.f ? ev : 0.01f * ev;
  float xv = __expf(ev);
  evals[i] = xv;
  atomicAdd(&esum[d], xv);
  atomicAdd(&dcnt[d], 1);
  int g = et[i] + ((i >= HALF) ? NREL : 0);
  int r = i / SLAB;
  atomicAdd(&hist[g * NREP + r], 1);
}

// cnt[g] = sum_r hist[g][r]
__global__ void k_cnt(const int* __restrict__ hist, int* __restrict__ cnt) {
  int g = blockIdx.x * 256 + threadIdx.x;
  if (g >= NGROUP) return;
  int s = 0;
  for (int r = 0; r < NREP; ++r) s += hist[g * NREP + r];
  cnt[g] = s;
}

// padded exclusive scan of group counts
__global__ void k_scan(const int* __restrict__ cnt, int* __restrict__ poffs) {
  __shared__ int tmp[1024];
  int t = threadIdx.x;
  int c = (t < NGROUP) ? cnt[t] : 0;
  int pc = (c + 31) & ~31;
  tmp[t] = pc;
  __syncthreads();
  #pragma unroll
  for (int off = 1; off < 1024; off <<= 1) {
    int v = (t >= off) ? tmp[t - off] : 0;
    __syncthreads();
    tmp[t] += v;
    __syncthreads();
  }
  poffs[t] = tmp[t] - pc;
}

// repbase[g][r] = poffs[g] + prefix_r hist[g][.]
__global__ void k_repbase(const int* __restrict__ hist, const int* __restrict__ poffs,
                          int* __restrict__ repbase) {
  int g = blockIdx.x * 256 + threadIdx.x;
  if (g >= NGROUP) return;
  int running = poffs[g];
  for (int r = 0; r < NREP; ++r) {
    repbase[g * NREP + r] = running;
    running += hist[g * NREP + r];
  }
}

__global__ void k_dscan1(const int* __restrict__ dcnt, int* __restrict__ dloc,
                         int* __restrict__ dtot) {
  __shared__ int tmp[1024];
  int t = threadIdx.x, i = blockIdx.x * 1024 + t;
  int v = (i < V) ? dcnt[i] : 0;
  tmp[t] = v;
  __syncthreads();
  #pragma unroll
  for (int off = 1; off < 1024; off <<= 1) {
    int u = (t >= off) ? tmp[t - off] : 0;
    __syncthreads();
    tmp[t] += u;
    __syncthreads();
  }
  if (i < V) dloc[i] = tmp[t] - v;
  if (t == 1023) dtot[blockIdx.x] = tmp[t];
}

__global__ void k_dscan2(const int* __restrict__ dtot, int* __restrict__ dboff) {
  __shared__ int tmp[128];
  int t = threadIdx.x;
  int v = (t < NBLK_D) ? dtot[t] : 0;
  tmp[t] = v;
  __syncthreads();
  #pragma unroll
  for (int off = 1; off < 128; off <<= 1) {
    int u = (t >= off) ? tmp[t - off] : 0;
    __syncthreads();
    tmp[t] += u;
    __syncthreads();
  }
  dboff[t] = tmp[t] - v;
}

__global__ void k_dscan3(const int* __restrict__ dloc, const int* __restrict__ dboff,
                         int* __restrict__ doffs) {
  int i = blockIdx.x * 1024 + threadIdx.x;
  if (i < V) doffs[i] = dloc[i] + dboff[i >> 10];
}

__global__ void k_scatter(const int* __restrict__ src, const int* __restrict__ dst,
                          const int* __restrict__ et, const float* __restrict__ ee,
                          const float* __restrict__ esum, const float* __restrict__ enorm,
                          const int* __restrict__ repbase, int* __restrict__ cnt2rep,
                          const int* __restrict__ doffs, int* __restrict__ dcnt2,
                          int* __restrict__ gsrc, int* __restrict__ dposA,
                          float* __restrict__ coef) {
  int i = blockIdx.x * 256 + threadIdx.x;
  if (i >= E) return;
  int g = et[i] + ((i >= HALF) ? NREL : 0);
  int r = i / SLAB;
  int pos = repbase[g * NREP + r] + atomicAdd(&cnt2rep[g * NREP + r], 1);
  int d = dst[i];
  gsrc[pos] = src[i];
  coef[pos] = ee[i] / esum[d] * enorm[i] * (1.f / 3.f);
  int dr = atomicAdd(&dcnt2[d], 1);
  dposA[pos] = doffs[d] + dr;
}

// grouped gather-GEMM + softmax + scaled write to dst-sorted msgb
__global__ __launch_bounds__(256) void k_msg3(const unsigned short* __restrict__ xb,
    const unsigned short* __restrict__ mbt, const int* __restrict__ cnt,
    const int* __restrict__ poffs, const int* __restrict__ gsrc,
    const int* __restrict__ dposA, const float* __restrict__ coef,
    const int* __restrict__ doffs, int loNode, int hiNode,
    unsigned short* __restrict__ msgb) {
  __shared__ uint4 Blds4[(D * 272) / 16];
  unsigned char* Bldsb = (unsigned char*)Blds4;
  int g = blockIdx.x;
  int c = cnt[g];
  if (c == 0) return;
  int tid = threadIdx.x;
  const uint4* Mg = (const uint4*)(mbt + (size_t)g * (D * D));
  #pragma unroll
  for (int i = 0; i < 8; ++i) {
    int idx = tid + i * 256;
    int row = idx >> 4, col = (idx & 15) * 16;
    Blds4[(row * 272 + col) >> 4] = Mg[idx];
  }
  __syncthreads();
  int b1 = doffs[loNode];
  int b2 = (hiNode >= V) ? E : doffs[hiNode];
  int wid = tid >> 6, ln = tid & 15, hi = (tid & 63) >> 4;
  int base0 = poffs[g];
  int nchunk = (c + 31) >> 5;
  for (int ch = wid; ch < nchunk; ch += 4) {
    int base = base0 + ch * 32;
    int sr0 = gsrc[base + ln];
    int sr1 = gsrc[base + 16 + ln];
    f4v cf0 = *(const f4v*)&coef[base + hi * 4];
    f4v cf1 = *(const f4v*)&coef[base + 16 + hi * 4];
    i4v dp0 = *(const i4v*)&dposA[base + hi * 4];
    i4v dp1 = *(const i4v*)&dposA[base + 16 + hi * 4];
    const unsigned short* xr0 = xb + (size_t)sr0 * D + hi * 8;
    const unsigned short* xr1 = xb + (size_t)sr1 * D + hi * 8;
    s8v af[2][4];
    #pragma unroll
    for (int kk = 0; kk < 4; ++kk) {
      af[0][kk] = *(const s8v*)(xr0 + kk * 32);
      af[1][kk] = *(const s8v*)(xr1 + kk * 32);
    }
    f4v acc[2][8];
    #pragma unroll
    for (int m = 0; m < 2; ++m)
      #pragma unroll
      for (int n = 0; n < 8; ++n) acc[m][n] = (f4v){0.f, 0.f, 0.f, 0.f};
    #pragma unroll
    for (int kk = 0; kk < 4; ++kk) {
      s8v bf[8];
      #pragma unroll
      for (int n = 0; n < 8; ++n) {
        int row = n * 16 + ln;
        bf[n] = *(const s8v*)(Bldsb + row * 272 + kk * 64 + hi * 16);
      }
      #pragma unroll
      for (int m = 0; m < 2; ++m)
        #pragma unroll
        for (int n = 0; n < 8; ++n)
          acc[m][n] = __builtin_amdgcn_mfma_f32_16x16x32_bf16(af[m][kk], bf[n], acc[m][n], 0, 0, 0);
    }
    #pragma unroll
    for (int m = 0; m < 2; ++m) {
      f4v cf = m ? cf1 : cf0;
      i4v dp = m ? dp1 : dp0;
      f4v mx = acc[m][0];
      #pragma unroll
      for (int n = 1; n < 8; ++n)
        #pragma unroll
        for (int j = 0; j < 4; ++j) mx[j] = fmaxf(mx[j], acc[m][n][j]);
      #pragma unroll
      for (int off = 1; off < 16; off <<= 1)
        #pragma unroll
        for (int j = 0; j < 4; ++j) mx[j] = fmaxf(mx[j], __shfl_xor(mx[j], off));
      f4v sum = (f4v){0.f, 0.f, 0.f, 0.f};
      #pragma unroll
      for (int n = 0; n < 8; ++n)
        #pragma unroll
        for (int j = 0; j < 4; ++j) {
          float e = __expf(acc[m][n][j] - mx[j]);
          acc[m][n][j] = e;
          sum[j] += e;
        }
      #pragma unroll
      for (int off = 1; off < 16; off <<= 1)
        #pragma unroll
        for (int j = 0; j < 4; ++j) sum[j] += __shfl_xor(sum[j], off);
      #pragma unroll
      for (int j = 0; j < 4; ++j) {
        int dpos = dp[j];
        if (dpos >= b1 && dpos < b2) {
          size_t rowb = (size_t)(dpos - b1) * D;
          float s = cf[j] / sum[j];
          #pragma unroll
          for (int n = 0; n < 8; ++n)
            msgb[rowb + n * 16 + ln] = f2bf(acc[m][n][j] * s);
        }
      }
    }
  }
}

// per-node segment sum of dst-sorted messages into out0
__global__ void k_sum(const unsigned short* __restrict__ msgb, const int* __restrict__ doffs,
                      const int* __restrict__ dcnt, float* __restrict__ out0,
                      int loNode, int hiNode) {
  int d = loNode + blockIdx.x * 4 + (threadIdx.x >> 6);
  if (d >= hiNode) return;
  int lane = threadIdx.x & 63;
  int b1 = doffs[loNode];
  int start = doffs[d] - b1, len = dcnt[d];
  float a0 = 0.f, a1 = 0.f;
  const unsigned short* mp = msgb + (size_t)start * D + lane * 2;
  for (int r = 0; r < len; ++r) {
    unsigned u = *(const unsigned*)(mp + (size_t)r * D);
    a0 += __uint_as_float(u << 16);
    a1 += __uint_as_float(u & 0xffff0000u);
  }
  float2* o = (float2*)&out0[(size_t)d * D + lane * 2];
  float2 v = *o;
  v.x += a0; v.y += a1;
  *o = v;
}

__global__ void k_bn_stats(const float* __restrict__ out0, float* __restrict__ colsum,
                           float* __restrict__ colsumsq) {
  int tid = threadIdx.x;
  int col = tid & 127;
  int v0 = blockIdx.x * 2 + (tid >> 7);
  float s = 0.f, s2 = 0.f;
  for (int v = v0; v < V; v += 1024) {
    float val = out0[(size_t)v * D + col];
    s += val; s2 += val * val;
  }
  atomicAdd(&colsum[col], s);
  atomicAdd(&colsumsq[col], s2);
}

__global__ void k_bn_norm(float* __restrict__ out0, const float* __restrict__ colsum,
                          const float* __restrict__ colsumsq) {
  int i = blockIdx.x * 256 + threadIdx.x;
  if (i >= V * D) return;
  int c = i & 127;
  float mean = colsum[c] * (1.f / V);
  float var = colsumsq[c] * (1.f / V) - mean * mean;
  out0[i] = (out0[i] - mean) * rsqrtf(var + 1e-5f);
}

extern "C" void kernel_launch(void* const* d_in, const int* in_sizes, int n_in,
                              void* d_out, int out_size, void* d_ws, size_t ws_size,
                              hipStream_t stream) {
  const float* x        = (const float*)d_in[0];
  const float* rel      = (const float*)d_in[4];
  const float* enorm    = (const float*)d_in[5];
  const float* in_w     = (const float*)d_in[6];
  const float* out_w    = (const float*)d_in[7];
  const float* loop_w   = (const float*)d_in[8];
  const float* w_rel    = (const float*)d_in[9];
  const float* loop_rel = (const float*)d_in[10];
  const float* attn_w   = (const float*)d_in[11];
  const float* bias     = (const float*)d_in[12];
  const int* src = (const int*)d_in[13];
  const int* dst = (const int*)d_in[14];
  const int* et  = (const int*)d_in[15];

  float* out0 = (float*)d_out;
  float* out1 = out0 + (size_t)V * D;

  float* base = (float*)d_ws;
  size_t off = 0;
  float* sxw = base + off;      off += V;
  float* dxw = base + off;      off += V;
  float* esum = base + off;     off += V;
  float* evals = base + off;    off += E;
  float* rw = base + off;       off += 512;
  float* colsum = base + off;   off += 128;
  float* colsumsq = base + off; off += 128;
  int* cnt = (int*)(base + off);   off += 1024;
  int* poffs = (int*)(base + off); off += 1024;
  int* hist = (int*)(base + off);     off += NGROUP * NREP;
  int* repbase = (int*)(base + off);  off += NGROUP * NREP;
  int* cnt2rep = (int*)(base + off);  off += NGROUP * NREP;
  int* dcnt = (int*)(base + off);  off += V;
  int* dcnt2 = (int*)(base + off); off += V;
  int* dloc = (int*)(base + off);  off += V;
  int* doffs = (int*)(base + off); off += V;
  int* dtot = (int*)(base + off);  off += 128;
  int* dboff = (int*)(base + off); off += 128;
  float* coef = base + off;        off += EP;
  int* gsrc = (int*)(base + off);  off += EP;
  int* dposA = (int*)(base + off); off += EP;
  unsigned short* mltb = (unsigned short*)(base + off); off += D * D / 2;
  unsigned short* relb = (unsigned short*)(base + off); off += NREL * D / 2;
  unsigned short* wtb  = (unsigned short*)(base + off); off += 2 * D * D / 2;
  unsigned short* xb   = (unsigned short*)(base + off); off += (size_t)V * D / 2;
  unsigned short* mbt  = (unsigned short*)(base + off); off += (size_t)NGROUP * D * D / 2;
  unsigned short* msgb = (unsigned short*)(base + off);

  size_t availF = (ws_size / 4 > off) ? (ws_size / 4 - off) : 0;
  int ns = 1;
  if ((size_t)EP * (D / 2) > availF) {
    ns = 2;
    while (ns < 64 && (size_t)(E / ns + 16384) * (D / 2) > availF) ns *= 2;
  }

  k_init<<<(EP + 255) / 256, 256, 0, stream>>>(esum, colsum, colsumsq, dcnt, dcnt2,
                                               hist, cnt2rep, coef, gsrc, dposA);
  k_rel<<<NREL, D, 0, stream>>>(rel, w_rel, attn_w, out1, rw);
  k_mloop<<<D, D, 0, stream>>>(loop_rel, loop_w, mltb);
  k_xb<<<(V * D / 4 + 255) / 256, 256, 0, stream>>>(x, xb);
  k_relb<<<(NREL * D + 255) / 256, 256, 0, stream>>>(rel, relb);
  k_wtb<<<256, D, 0, stream>>>(in_w, out_w, wtb);
  k_mbt2<<<NGROUP, 256, 0, stream>>>(relb, wtb, mbt);
  k_proj<<<640, 256, 0, stream>>>(x, attn_w, sxw, dxw);
  k_lgemm<<<V / 128, 256, 0, stream>>>(xb, mltb, bias, out0);
  k_edge<<<(E + 255) / 256, 256, 0, stream>>>(src, dst, et, sxw, dxw, rw,
                                              evals, esum, dcnt, hist);
  k_cnt<<<(NGROUP + 255) / 256, 256, 0, stream>>>(hist, cnt);
  k_scan<<<1, 1024, 0, stream>>>(cnt, poffs);
  k_repbase<<<(NGROUP + 255) / 256, 256, 0, stream>>>(hist, poffs, repbase);
  k_dscan1<<<NBLK_D, 1024, 0, stream>>>(dcnt, dloc, dtot);
  k_dscan2<<<1, 128, 0, stream>>>(dtot, dboff);
  k_dscan3<<<NBLK_D, 1024, 0, stream>>>(dloc, dboff, doffs);
  k_scatter<<<(E + 255) / 256, 256, 0, stream>>>(src, dst, et, evals, esum, enorm,
                                                 repbase, cnt2rep, doffs, dcnt2,
                                                 gsrc, dposA, coef);
  int Vs = V / ns;
  for (int s = 0; s < ns; ++s) {
    int lo = s * Vs, hi = (s == ns - 1) ? V : (s + 1) * Vs;
    k_msg3<<<NGROUP, 256, 0, stream>>>(xb, mbt, cnt, poffs, gsrc, dposA, coef,
                                       doffs, lo, hi, msgb);
    k_sum<<<(Vs + 3) / 4, 256, 0, stream>>>(msgb, doffs, dcnt, out0, lo, hi);
  }
  k_bn_stats<<<512, 256, 0, stream>>>(out0, colsum, colsumsq);
  k_bn_norm<<<(V * D + 255) / 256, 256, 0, stream>>>(out0, colsum, colsumsq);
}